// Round 7
// baseline (326.081 us; speedup 1.0000x reference)
//
#include <hip/hip_runtime.h>
#include <hip/hip_bf16.h>

#define B_N 4
#define S_LEN 2048
#define D_MODEL 1024
#define N_HEAD 16
#define D_HEAD 64
#define M_ROWS (B_N * S_LEN) /* 8192 */

typedef short bf16x8 __attribute__((ext_vector_type(8)));
typedef short bf16x4 __attribute__((ext_vector_type(4)));
typedef float f32x4 __attribute__((ext_vector_type(4)));

#if __has_builtin(__builtin_amdgcn_mfma_f32_16x16x16bf16_1k)
#define HAVE_MFMA16 1
#else
#define HAVE_MFMA16 0
#endif

__device__ __forceinline__ unsigned short f2bf(float f) {
  union { float f; unsigned int u; } v; v.f = f;
  unsigned int r = v.u + 0x7FFFu + ((v.u >> 16) & 1u);
  return (unsigned short)(r >> 16);
}
__device__ __forceinline__ float bf2f(unsigned short u) {
  union { unsigned int u; float f; } v; v.u = ((unsigned int)u) << 16;
  return v.f;
}
// packed f32x2 -> bf16x2 (v_cvt_pk_bf16_f32, RNE)
__device__ __forceinline__ unsigned int pkbf(float a, float b) {
  union { __hip_bfloat162 h; unsigned int u; } cv;
  cv.h = __float22bfloat162_rn(make_float2(a, b));
  return cv.u;
}
__device__ __forceinline__ bf16x8 ld8(const unsigned short* p) {
  return *reinterpret_cast<const bf16x8*>(p);
}
__device__ __forceinline__ bf16x4 ld4(const unsigned short* p) {
  return *reinterpret_cast<const bf16x4*>(p);
}
__device__ __forceinline__ void glds16(const unsigned short* g, unsigned short* l) {
  __builtin_amdgcn_global_load_lds(
      (const __attribute__((address_space(1))) unsigned int*)g,
      (__attribute__((address_space(3))) unsigned int*)l, 16, 0, 0);
}

// ---------------------------------------------------------------- rope table
__global__ __launch_bounds__(256) void rope_tab_k(const int* __restrict__ pos,
                                                  float2* __restrict__ tab) {
  const int idx = blockIdx.x * 256 + threadIdx.x;
  const int s = idx >> 5;
  const int i = idx & 31;
  const float inv = exp2f(-(float)i * 0.41524101186092029f);  // log2(1e4)/32
  const float ang = (float)pos[s] * inv;
  tab[idx] = make_float2(cosf(ang), sinf(ang));
}

// ---------------------------------------------------------------- cast x
__global__ __launch_bounds__(256) void cast_k(const float* __restrict__ X,
                                              unsigned short* __restrict__ Y) {
  const size_t i = ((size_t)blockIdx.x * 256 + threadIdx.x) * 8;
  const float4 a = *reinterpret_cast<const float4*>(X + i);
  const float4 b = *reinterpret_cast<const float4*>(X + i + 4);
  union { unsigned int u[4]; uint4 v; } o;
  o.u[0] = pkbf(a.x, a.y); o.u[1] = pkbf(a.z, a.w);
  o.u[2] = pkbf(b.x, b.y); o.u[3] = pkbf(b.z, b.w);
  *reinterpret_cast<uint4*>(Y + i) = o.v;
}

// ---------------------------------------------------------------- transpose
__global__ __launch_bounds__(256) void wtrans_k(
    const float* __restrict__ W0, const float* __restrict__ W1,
    const float* __restrict__ W2, const float* __restrict__ W3,
    unsigned short* __restrict__ T0, unsigned short* __restrict__ T1,
    unsigned short* __restrict__ T2, unsigned short* __restrict__ T3) {
  const int z = blockIdx.z;
  const float* __restrict__ W = (z == 0) ? W0 : (z == 1) ? W1 : (z == 2) ? W2 : W3;
  unsigned short* __restrict__ T = (z == 0) ? T0 : (z == 1) ? T1 : (z == 2) ? T2 : T3;
  __shared__ __align__(16) unsigned short tile[64][72];
  const int kb = blockIdx.x * 64;
  const int nb = blockIdx.y * 64;
#pragma unroll
  for (int it = 0; it < 2; ++it) {
    const int chunk = it * 256 + threadIdx.x;
    const int r = chunk >> 3;
    const int c8 = (chunk & 7) * 8;
    const float* src = W + (size_t)(kb + r) * D_MODEL + nb + c8;
    const float4 a = *reinterpret_cast<const float4*>(src);
    const float4 b = *reinterpret_cast<const float4*>(src + 4);
    union { unsigned int u[4]; uint4 v; } o;
    o.u[0] = pkbf(a.x, a.y); o.u[1] = pkbf(a.z, a.w);
    o.u[2] = pkbf(b.x, b.y); o.u[3] = pkbf(b.z, b.w);
    *reinterpret_cast<uint4*>(&tile[r][c8]) = o.v;
  }
  __syncthreads();
#pragma unroll
  for (int it = 0; it < 2; ++it) {
    const int chunk = it * 256 + threadIdx.x;
    const int n = chunk >> 3;
    const int k8 = (chunk & 7) * 8;
    __align__(16) unsigned short vals[8];
#pragma unroll
    for (int j = 0; j < 8; ++j) vals[j] = tile[k8 + j][n];
    *reinterpret_cast<uint4*>(T + (size_t)(nb + n) * D_MODEL + kb + k8) =
        *reinterpret_cast<const uint4*>(vals);
  }
}

// ---------------------------------------------------------------- GEMM
// 128x128 tile, BK=32, global_load_lds staging, 4 waves x (4x4 frags).
// mode 0 (QKV, N=3072): [0,1024)->Qo (rope, pre-scaled by 0.125*log2e),
//   [1024,2048)->Ko (rope), [2048,3072)->VTo transposed. Full-line stores
//   via wave-private LDS tile. mode 1: fp32 out.
__global__ __launch_bounds__(256) void gemm2_k(
    const unsigned short* __restrict__ A, const unsigned short* __restrict__ W,
    unsigned short* __restrict__ Qo, unsigned short* __restrict__ Ko,
    unsigned short* __restrict__ VTo, float* __restrict__ OF,
    const float2* __restrict__ tab, const int mode) {
  __shared__ __align__(16) unsigned short smem[4][64][68];
  unsigned short* As = &smem[0][0][0];
  unsigned short* Bs = As + 128 * 32;

  const int tid = threadIdx.x;
  const int lane = tid & 63;
  const int w = tid >> 6;
  const int l15 = lane & 15;
  const int l4 = lane >> 4;

  const int row0 = blockIdx.x * 128;
  const int col0 = blockIdx.y * 128;

  const int srow = w * 32 + (lane >> 2);
  const int scol = (lane & 3) * 8;
  const unsigned short* ga = A + (size_t)(row0 + srow) * D_MODEL + scol;
  const unsigned short* gb = W + (size_t)(col0 + srow) * D_MODEL + scol;
  unsigned short* la = &As[(w * 32) * 32];
  unsigned short* lb = &Bs[(w * 32) * 32];

  const int wrow = (w & 1) * 64;
  const int wcol = (w >> 1) * 64;

  f32x4 acc[4][4];
  const f32x4 fz = {0.f, 0.f, 0.f, 0.f};
#pragma unroll
  for (int m = 0; m < 4; ++m)
#pragma unroll
    for (int n = 0; n < 4; ++n) acc[m][n] = fz;

  for (int kb = 0; kb < D_MODEL; kb += 32) {
    glds16(ga + kb, la);
    glds16(ga + 16 * D_MODEL + kb, la + 16 * 32);
    glds16(gb + kb, lb);
    glds16(gb + 16 * D_MODEL + kb, lb + 16 * 32);
    __syncthreads();
    bf16x8 af[4], bfr[4];
#pragma unroll
    for (int m = 0; m < 4; ++m) af[m] = ld8(&As[(wrow + m * 16 + l15) * 32 + l4 * 8]);
#pragma unroll
    for (int n = 0; n < 4; ++n) bfr[n] = ld8(&Bs[(wcol + n * 16 + l15) * 32 + l4 * 8]);
#pragma unroll
    for (int m = 0; m < 4; ++m)
#pragma unroll
      for (int n = 0; n < 4; ++n)
        acc[m][n] = __builtin_amdgcn_mfma_f32_16x16x32_bf16(af[m], bfr[n], acc[m][n], 0, 0, 0);
    __syncthreads();
  }

  if (mode == 1) {
#pragma unroll
    for (int n = 0; n < 4; ++n) {
      const int gcol = col0 + wcol + n * 16 + l15;
#pragma unroll
      for (int m = 0; m < 4; ++m)
#pragma unroll
        for (int r = 0; r < 4; ++r)
          OF[(size_t)(row0 + wrow + m * 16 + l4 * 4 + r) * D_MODEL + gcol] = acc[m][n][r];
    }
    return;
  }

  unsigned short (*T)[68] = (unsigned short(*)[68]) & smem[w];  // wave-private
  const bool isV = (col0 >= 2048);
  if (!isV) {
#pragma unroll
    for (int m = 0; m < 4; ++m)
#pragma unroll
      for (int n = 0; n < 4; ++n)
#pragma unroll
        for (int r = 0; r < 4; ++r)
          T[m * 16 + l4 * 4 + r][n * 16 + l15] = f2bf(acc[m][n][r]);
  } else {
#pragma unroll
    for (int m = 0; m < 4; ++m)
#pragma unroll
      for (int n = 0; n < 4; ++n)
#pragma unroll
        for (int r = 0; r < 4; ++r)
          T[n * 16 + l15][m * 16 + l4 * 4 + r] = f2bf(acc[m][n][r]);
  }

  const int lr = lane >> 3;
  const int lc = lane & 7;
  if (!isV) {
    const bool isQ = (col0 < 1024);
    unsigned short* O = isQ ? Qo : Ko;
    // fold softmax scale into Q: 1/sqrt(64) * log2(e)
    const float qs = isQ ? 0.18033688011112042f : 1.0f;
    const int cbase = (col0 & 1023) + wcol;
#pragma unroll
    for (int rg = 0; rg < 8; ++rg) {
      const int trow = rg * 8 + lr;
      const int grow = row0 + wrow + trow;
      const int s = grow & (S_LEN - 1);
      const bf16x8 vv = ld8(&T[trow][lc * 8]);
      const float4 tA = *reinterpret_cast<const float4*>(&tab[s * 32 + lc * 4]);
      const float4 tB = *reinterpret_cast<const float4*>(&tab[s * 32 + lc * 4 + 2]);
      float x[8];
#pragma unroll
      for (int j = 0; j < 8; ++j) x[j] = bf2f((unsigned short)vv[j]);
      union { unsigned int u[4]; uint4 v; } o;
      o.u[0] = pkbf((x[0] * tA.x - x[1] * tA.y) * qs, (x[0] * tA.y + x[1] * tA.x) * qs);
      o.u[1] = pkbf((x[2] * tA.z - x[3] * tA.w) * qs, (x[2] * tA.w + x[3] * tA.z) * qs);
      o.u[2] = pkbf((x[4] * tB.x - x[5] * tB.y) * qs, (x[4] * tB.y + x[5] * tB.x) * qs);
      o.u[3] = pkbf((x[6] * tB.z - x[7] * tB.w) * qs, (x[6] * tB.w + x[7] * tB.z) * qs);
      *reinterpret_cast<uint4*>(O + (size_t)grow * D_MODEL + cbase + lc * 8) = o.v;
    }
  } else {
    const int vc0 = (col0 - 2048) + wcol;
    const int h = vc0 >> 6;
    const int b = row0 >> 11;
    const int s0 = (row0 & (S_LEN - 1)) + wrow;
#pragma unroll
    for (int rg = 0; rg < 8; ++rg) {
      const int dk = rg * 8 + lr;
      const bf16x8 vv = ld8(&T[dk][lc * 8]);
      *reinterpret_cast<bf16x8*>(
          VTo + ((size_t)((b << 4) + h) * 64 + dk) * S_LEN + s0 + lc * 8) = vv;
    }
  }
}

// ---------------------------------------------------------------- attention
// Flash, causal, no running max (Q pre-scaled by 0.125*log2e; scores O(5)).
// Computes S^T (A=K, B=Q): C-layout lane holds q=l15, keys=l4*4+r — which IS
// the B-fragment layout of mfma_f32_16x16x16bf16_1k, so P feeds PV fully
// in-register (no LDS transpose). K/V staging double-buffered through regs.
// Block = q-tiles (pair, 15-pair) -> uniform 34 key-tiles/block.
__global__ __launch_bounds__(256) void attn4_k(
    const unsigned short* __restrict__ Q, const unsigned short* __restrict__ K,
    const unsigned short* __restrict__ VT, unsigned short* __restrict__ O) {
  const int pair = blockIdx.x;  // 0..7
  const int h = blockIdx.y;
  const int b = blockIdx.z;
  const int tid = threadIdx.x;
  const int w = tid >> 6;
  const int lane = tid & 63;
  const int l15 = lane & 15;
  const int l4 = lane >> 4;

  __shared__ __align__(16) unsigned short Ks[64][72];
  __shared__ __align__(16) unsigned short Vs[64][72];  // Vs[dk][key]
#if !HAVE_MFMA16
  __shared__ __align__(16) unsigned short Ps[4][32][72];
#endif

  const f32x4 fz = {0.f, 0.f, 0.f, 0.f};
  const unsigned short* kbase = K + (size_t)b * S_LEN * D_MODEL + h * D_HEAD;
  const unsigned short* vbase = VT + (size_t)((b << 4) + h) * 64 * S_LEN;

  const int rr = tid >> 3;        // staging row 0..31 (it adds 32)
  const int c8 = (tid & 7) * 8;   // staging 8-short chunk

  for (int half = 0; half < 2; ++half) {
    const int qt = half ? (15 - pair) : pair;
    const int qb = qt * 128;
    const int qw0 = qb + w * 32;

    bf16x8 qf[2][2];
#pragma unroll
    for (int t = 0; t < 2; ++t)
#pragma unroll
      for (int kc = 0; kc < 2; ++kc)
        qf[t][kc] = ld8(Q + (size_t)(b * S_LEN + qw0 + t * 16 + l15) * D_MODEL +
                        h * D_HEAD + kc * 32 + l4 * 8);

    f32x4 o[4][2];
#pragma unroll
    for (int d = 0; d < 4; ++d)
#pragma unroll
      for (int t = 0; t < 2; ++t) o[d][t] = fz;
    float lsum[2] = {0.f, 0.f};

    const int nkt = qb / 64 + 2;
    uint4 kreg[2], vreg[2];
    // prefetch tile 0
#pragma unroll
    for (int it = 0; it < 2; ++it) {
      kreg[it] = *reinterpret_cast<const uint4*>(kbase + (size_t)(rr + it * 32) * D_MODEL + c8);
      vreg[it] = *reinterpret_cast<const uint4*>(vbase + (size_t)(rr + it * 32) * S_LEN + c8);
    }

    for (int kt = 0; kt < nkt; ++kt) {
      const int kb0 = kt * 64;
#pragma unroll
      for (int it = 0; it < 2; ++it) {
        *reinterpret_cast<uint4*>(&Ks[rr + it * 32][c8]) = kreg[it];
        *reinterpret_cast<uint4*>(&Vs[rr + it * 32][c8]) = vreg[it];
      }
      __syncthreads();
      if (kt + 1 < nkt) {  // prefetch next tile; latency hides behind compute
        const int nb0 = kb0 + 64;
#pragma unroll
        for (int it = 0; it < 2; ++it) {
          kreg[it] = *reinterpret_cast<const uint4*>(kbase + (size_t)(nb0 + rr + it * 32) * D_MODEL + c8);
          vreg[it] = *reinterpret_cast<const uint4*>(vbase + (size_t)(rr + it * 32) * S_LEN + nb0 + c8);
        }
      }

      if (kb0 <= qw0 + 31) {
        // ---- S^T = K Q^T : C-layout lane holds q=l15, key=kb0+n*16+l4*4+r
        bf16x8 kf[4][2];
#pragma unroll
        for (int n = 0; n < 4; ++n)
#pragma unroll
          for (int kc = 0; kc < 2; ++kc)
            kf[n][kc] = ld8(&Ks[n * 16 + l15][kc * 32 + l4 * 8]);
        f32x4 s[2][4];
#pragma unroll
        for (int t = 0; t < 2; ++t)
#pragma unroll
          for (int n = 0; n < 4; ++n) {
            f32x4 a0 = __builtin_amdgcn_mfma_f32_16x16x32_bf16(kf[n][0], qf[t][0], fz, 0, 0, 0);
            s[t][n] = __builtin_amdgcn_mfma_f32_16x16x32_bf16(kf[n][1], qf[t][1], a0, 0, 0, 0);
          }

        // ---- exp2 + causal mask + per-lane row-sum + pack to bf16
        bf16x4 pf[2][4];
#pragma unroll
        for (int t = 0; t < 2; ++t) {
          const bool full = (kb0 + 63 <= qw0 + t * 16);
          const int q = qw0 + t * 16 + l15;
          float su = lsum[t];
#pragma unroll
          for (int n = 0; n < 4; ++n) {
            float e[4];
            if (full) {
#pragma unroll
              for (int r = 0; r < 4; ++r) e[r] = exp2f(s[t][n][r]);
            } else {
#pragma unroll
              for (int r = 0; r < 4; ++r) {
                const int key = kb0 + n * 16 + l4 * 4 + r;
                const float v = exp2f(s[t][n][r]);
                e[r] = (key <= q) ? v : 0.f;
              }
            }
            su += (e[0] + e[1]) + (e[2] + e[3]);
            union { unsigned int u[2]; bf16x4 v; } pk;
            pk.u[0] = pkbf(e[0], e[1]);
            pk.u[1] = pkbf(e[2], e[3]);
            pf[t][n] = pk.v;
          }
          lsum[t] = su;
        }

        // ---- O^T += V^T P^T
#if HAVE_MFMA16
#pragma unroll
        for (int d = 0; d < 4; ++d) {
          bf16x4 vfc[4];
#pragma unroll
          for (int c = 0; c < 4; ++c) vfc[c] = ld4(&Vs[d * 16 + l15][c * 16 + l4 * 4]);
#pragma unroll
          for (int t = 0; t < 2; ++t)
#pragma unroll
            for (int c = 0; c < 4; ++c)
              o[d][t] = __builtin_amdgcn_mfma_f32_16x16x16bf16_1k(vfc[c], pf[t][c], o[d][t], 0, 0, 0);
        }
#else
        // fallback: vectorized LDS roundtrip, K=32 MFMA
#pragma unroll
        for (int t = 0; t < 2; ++t)
#pragma unroll
          for (int n = 0; n < 4; ++n)
            *reinterpret_cast<bf16x4*>(&Ps[w][t * 16 + l15][n * 16 + l4 * 4]) = pf[t][n];
        bf16x8 pfr[2][2], vf8[4][2];
#pragma unroll
        for (int t = 0; t < 2; ++t)
#pragma unroll
          for (int kc = 0; kc < 2; ++kc)
            pfr[t][kc] = ld8(&Ps[w][t * 16 + l15][kc * 32 + l4 * 8]);
#pragma unroll
        for (int d = 0; d < 4; ++d)
#pragma unroll
          for (int kc = 0; kc < 2; ++kc)
            vf8[d][kc] = ld8(&Vs[d * 16 + l15][kc * 32 + l4 * 8]);
#pragma unroll
        for (int d = 0; d < 4; ++d)
#pragma unroll
          for (int t = 0; t < 2; ++t) {
            o[d][t] = __builtin_amdgcn_mfma_f32_16x16x32_bf16(vf8[d][0], pfr[t][0], o[d][t], 0, 0, 0);
            o[d][t] = __builtin_amdgcn_mfma_f32_16x16x32_bf16(vf8[d][1], pfr[t][1], o[d][t], 0, 0, 0);
          }
#endif
      }
      __syncthreads();
    }

    // lsum lives per-lane at q=l15; reduce across the 4 quads (bits 4,5)
#pragma unroll
    for (int t = 0; t < 2; ++t) {
      float s = lsum[t];
      s += __shfl_xor(s, 16);
      s += __shfl_xor(s, 32);
      const float li = 1.0f / s;
      unsigned short* op = O + (size_t)(b * S_LEN + qw0 + t * 16 + l15) * D_MODEL +
                           h * D_HEAD + l4 * 4;
#pragma unroll
      for (int d = 0; d < 4; ++d) {
        union { unsigned int u[2]; uint2 v; } ov;
        ov.u[0] = pkbf(o[d][t][0] * li, o[d][t][1] * li);
        ov.u[1] = pkbf(o[d][t][2] * li, o[d][t][3] * li);
        *reinterpret_cast<uint2*>(op + d * 16) = ov.v;
      }
    }
  }
}

// ---------------------------------------------------------------- launch
extern "C" void kernel_launch(void* const* d_in, const int* in_sizes, int n_in,
                              void* d_out, int out_size, void* d_ws, size_t ws_size,
                              hipStream_t stream) {
  const float* x  = (const float*)d_in[0];
  const float* Wq = (const float*)d_in[1];
  const float* Wk = (const float*)d_in[2];
  const float* Wv = (const float*)d_in[3];
  const float* Wo = (const float*)d_in[4];
  const int* pos  = (const int*)d_in[5];
  float* out = (float*)d_out;

  char* ws = (char*)d_ws;
  const size_t big = (size_t)M_ROWS * D_MODEL * 2;  // 16 MiB
  const size_t wsz = (size_t)D_MODEL * D_MODEL * 2; // 2 MiB
  unsigned short* xb  = (unsigned short*)(ws + 0 * big);
  unsigned short* Qb  = (unsigned short*)(ws + 1 * big);  // attn out aliases Qb
  unsigned short* Kb  = (unsigned short*)(ws + 2 * big);
  unsigned short* VT  = (unsigned short*)(ws + 3 * big);
  unsigned short* Wqkvt = (unsigned short*)(ws + 4 * big);
  unsigned short* Wot   = (unsigned short*)(ws + 4 * big + 3 * wsz);
  float2* tab = (float2*)d_out;  // free scratch until final projection

  rope_tab_k<<<dim3(S_LEN * 32 / 256), 256, 0, stream>>>(pos, tab);
  cast_k<<<dim3(M_ROWS * D_MODEL / 2048), 256, 0, stream>>>(x, xb);
  wtrans_k<<<dim3(16, 16, 4), 256, 0, stream>>>(
      Wq, Wk, Wv, Wo, Wqkvt, Wqkvt + (size_t)D_MODEL * D_MODEL,
      Wqkvt + 2 * (size_t)D_MODEL * D_MODEL, Wot);
  gemm2_k<<<dim3(M_ROWS / 128, 3 * D_MODEL / 128), 256, 0, stream>>>(
      xb, Wqkvt, Qb, Kb, VT, nullptr, tab, 0);
  attn4_k<<<dim3(8, N_HEAD, B_N), 256, 0, stream>>>(Qb, Kb, VT, Qb);
  gemm2_k<<<dim3(M_ROWS / 128, D_MODEL / 128), 256, 0, stream>>>(
      Qb, Wot, nullptr, nullptr, nullptr, out, nullptr, 1);
}

// Round 8
// 301.434 us; speedup vs baseline: 1.0818x; 1.0818x over previous
//
#include <hip/hip_runtime.h>
#include <hip/hip_bf16.h>

#define B_N 4
#define S_LEN 2048
#define D_MODEL 1024
#define N_HEAD 16
#define D_HEAD 64
#define M_ROWS (B_N * S_LEN) /* 8192 */

typedef short bf16x8 __attribute__((ext_vector_type(8)));
typedef short bf16x4 __attribute__((ext_vector_type(4)));
typedef float f32x4 __attribute__((ext_vector_type(4)));

#if __has_builtin(__builtin_amdgcn_mfma_f32_16x16x16bf16_1k)
#define HAVE_MFMA16 1
#else
#define HAVE_MFMA16 0
#endif

__device__ __forceinline__ unsigned short f2bf(float f) {
  union { float f; unsigned int u; } v; v.f = f;
  unsigned int r = v.u + 0x7FFFu + ((v.u >> 16) & 1u);
  return (unsigned short)(r >> 16);
}
__device__ __forceinline__ float bf2f(unsigned short u) {
  union { unsigned int u; float f; } v; v.u = ((unsigned int)u) << 16;
  return v.f;
}
// packed f32x2 -> bf16x2 (v_cvt_pk_bf16_f32, RNE)
__device__ __forceinline__ unsigned int pkbf(float a, float b) {
  union { __hip_bfloat162 h; unsigned int u; } cv;
  cv.h = __float22bfloat162_rn(make_float2(a, b));
  return cv.u;
}
__device__ __forceinline__ bf16x8 ld8(const unsigned short* p) {
  return *reinterpret_cast<const bf16x8*>(p);
}
__device__ __forceinline__ bf16x4 ld4(const unsigned short* p) {
  return *reinterpret_cast<const bf16x4*>(p);
}
__device__ __forceinline__ void glds16(const unsigned short* g, unsigned short* l) {
  __builtin_amdgcn_global_load_lds(
      (const __attribute__((address_space(1))) unsigned int*)g,
      (__attribute__((address_space(3))) unsigned int*)l, 16, 0, 0);
}

// ---------------------------------------------------------------- rope table
__global__ __launch_bounds__(256) void rope_tab_k(const int* __restrict__ pos,
                                                  float2* __restrict__ tab) {
  const int idx = blockIdx.x * 256 + threadIdx.x;
  const int s = idx >> 5;
  const int i = idx & 31;
  const float inv = exp2f(-(float)i * 0.41524101186092029f);  // log2(1e4)/32
  const float ang = (float)pos[s] * inv;
  tab[idx] = make_float2(cosf(ang), sinf(ang));
}

// ---------------------------------------------------------------- cast x
__global__ __launch_bounds__(256) void cast_k(const float* __restrict__ X,
                                              unsigned short* __restrict__ Y) {
  const size_t i = ((size_t)blockIdx.x * 256 + threadIdx.x) * 8;
  const float4 a = *reinterpret_cast<const float4*>(X + i);
  const float4 b = *reinterpret_cast<const float4*>(X + i + 4);
  union { unsigned int u[4]; uint4 v; } o;
  o.u[0] = pkbf(a.x, a.y); o.u[1] = pkbf(a.z, a.w);
  o.u[2] = pkbf(b.x, b.y); o.u[3] = pkbf(b.z, b.w);
  *reinterpret_cast<uint4*>(Y + i) = o.v;
}

// ---------------------------------------------------------------- transpose
__global__ __launch_bounds__(256) void wtrans_k(
    const float* __restrict__ W0, const float* __restrict__ W1,
    const float* __restrict__ W2, const float* __restrict__ W3,
    unsigned short* __restrict__ T0, unsigned short* __restrict__ T1,
    unsigned short* __restrict__ T2, unsigned short* __restrict__ T3) {
  const int z = blockIdx.z;
  const float* __restrict__ W = (z == 0) ? W0 : (z == 1) ? W1 : (z == 2) ? W2 : W3;
  unsigned short* __restrict__ T = (z == 0) ? T0 : (z == 1) ? T1 : (z == 2) ? T2 : T3;
  __shared__ __align__(16) unsigned short tile[64][72];
  const int kb = blockIdx.x * 64;
  const int nb = blockIdx.y * 64;
#pragma unroll
  for (int it = 0; it < 2; ++it) {
    const int chunk = it * 256 + threadIdx.x;
    const int r = chunk >> 3;
    const int c8 = (chunk & 7) * 8;
    const float* src = W + (size_t)(kb + r) * D_MODEL + nb + c8;
    const float4 a = *reinterpret_cast<const float4*>(src);
    const float4 b = *reinterpret_cast<const float4*>(src + 4);
    union { unsigned int u[4]; uint4 v; } o;
    o.u[0] = pkbf(a.x, a.y); o.u[1] = pkbf(a.z, a.w);
    o.u[2] = pkbf(b.x, b.y); o.u[3] = pkbf(b.z, b.w);
    *reinterpret_cast<uint4*>(&tile[r][c8]) = o.v;
  }
  __syncthreads();
#pragma unroll
  for (int it = 0; it < 2; ++it) {
    const int chunk = it * 256 + threadIdx.x;
    const int n = chunk >> 3;
    const int k8 = (chunk & 7) * 8;
    __align__(16) unsigned short vals[8];
#pragma unroll
    for (int j = 0; j < 8; ++j) vals[j] = tile[k8 + j][n];
    *reinterpret_cast<uint4*>(T + (size_t)(nb + n) * D_MODEL + kb + k8) =
        *reinterpret_cast<const uint4*>(vals);
  }
}

// ---------------------------------------------------------------- GEMM
// 128x128 tile, BK=32, global_load_lds staging, 4 waves x (4x4 frags).
// mode 0 (QKV, N=3072): [0,1024)->Qo (rope, pre-scaled by 0.125*log2e),
//   [1024,2048)->Ko (rope), [2048,3072)->VTo transposed. Full-line stores
//   via wave-private LDS tile. mode 1: fp32 out.
__global__ __launch_bounds__(256) void gemm2_k(
    const unsigned short* __restrict__ A, const unsigned short* __restrict__ W,
    unsigned short* __restrict__ Qo, unsigned short* __restrict__ Ko,
    unsigned short* __restrict__ VTo, float* __restrict__ OF,
    const float2* __restrict__ tab, const int mode) {
  __shared__ __align__(16) unsigned short smem[4][64][68];
  unsigned short* As = &smem[0][0][0];
  unsigned short* Bs = As + 128 * 32;

  const int tid = threadIdx.x;
  const int lane = tid & 63;
  const int w = tid >> 6;
  const int l15 = lane & 15;
  const int l4 = lane >> 4;

  const int row0 = blockIdx.x * 128;
  const int col0 = blockIdx.y * 128;

  const int srow = w * 32 + (lane >> 2);
  const int scol = (lane & 3) * 8;
  const unsigned short* ga = A + (size_t)(row0 + srow) * D_MODEL + scol;
  const unsigned short* gb = W + (size_t)(col0 + srow) * D_MODEL + scol;
  unsigned short* la = &As[(w * 32) * 32];
  unsigned short* lb = &Bs[(w * 32) * 32];

  const int wrow = (w & 1) * 64;
  const int wcol = (w >> 1) * 64;

  f32x4 acc[4][4];
  const f32x4 fz = {0.f, 0.f, 0.f, 0.f};
#pragma unroll
  for (int m = 0; m < 4; ++m)
#pragma unroll
    for (int n = 0; n < 4; ++n) acc[m][n] = fz;

  for (int kb = 0; kb < D_MODEL; kb += 32) {
    glds16(ga + kb, la);
    glds16(ga + 16 * D_MODEL + kb, la + 16 * 32);
    glds16(gb + kb, lb);
    glds16(gb + 16 * D_MODEL + kb, lb + 16 * 32);
    __syncthreads();
    bf16x8 af[4], bfr[4];
#pragma unroll
    for (int m = 0; m < 4; ++m) af[m] = ld8(&As[(wrow + m * 16 + l15) * 32 + l4 * 8]);
#pragma unroll
    for (int n = 0; n < 4; ++n) bfr[n] = ld8(&Bs[(wcol + n * 16 + l15) * 32 + l4 * 8]);
#pragma unroll
    for (int m = 0; m < 4; ++m)
#pragma unroll
      for (int n = 0; n < 4; ++n)
        acc[m][n] = __builtin_amdgcn_mfma_f32_16x16x32_bf16(af[m], bfr[n], acc[m][n], 0, 0, 0);
    __syncthreads();
  }

  if (mode == 1) {
#pragma unroll
    for (int n = 0; n < 4; ++n) {
      const int gcol = col0 + wcol + n * 16 + l15;
#pragma unroll
      for (int m = 0; m < 4; ++m)
#pragma unroll
        for (int r = 0; r < 4; ++r)
          OF[(size_t)(row0 + wrow + m * 16 + l4 * 4 + r) * D_MODEL + gcol] = acc[m][n][r];
    }
    return;
  }

  unsigned short (*T)[68] = (unsigned short(*)[68]) & smem[w];  // wave-private
  const bool isV = (col0 >= 2048);
  if (!isV) {
#pragma unroll
    for (int m = 0; m < 4; ++m)
#pragma unroll
      for (int n = 0; n < 4; ++n)
#pragma unroll
        for (int r = 0; r < 4; ++r)
          T[m * 16 + l4 * 4 + r][n * 16 + l15] = f2bf(acc[m][n][r]);
  } else {
#pragma unroll
    for (int m = 0; m < 4; ++m)
#pragma unroll
      for (int n = 0; n < 4; ++n)
#pragma unroll
        for (int r = 0; r < 4; ++r)
          T[n * 16 + l15][m * 16 + l4 * 4 + r] = f2bf(acc[m][n][r]);
  }

  const int lr = lane >> 3;
  const int lc = lane & 7;
  if (!isV) {
    const bool isQ = (col0 < 1024);
    unsigned short* O = isQ ? Qo : Ko;
    // fold softmax scale into Q: 1/sqrt(64) * log2(e)
    const float qs = isQ ? 0.18033688011112042f : 1.0f;
    const int cbase = (col0 & 1023) + wcol;
#pragma unroll
    for (int rg = 0; rg < 8; ++rg) {
      const int trow = rg * 8 + lr;
      const int grow = row0 + wrow + trow;
      const int s = grow & (S_LEN - 1);
      const bf16x8 vv = ld8(&T[trow][lc * 8]);
      const float4 tA = *reinterpret_cast<const float4*>(&tab[s * 32 + lc * 4]);
      const float4 tB = *reinterpret_cast<const float4*>(&tab[s * 32 + lc * 4 + 2]);
      float x[8];
#pragma unroll
      for (int j = 0; j < 8; ++j) x[j] = bf2f((unsigned short)vv[j]);
      union { unsigned int u[4]; uint4 v; } o;
      o.u[0] = pkbf((x[0] * tA.x - x[1] * tA.y) * qs, (x[0] * tA.y + x[1] * tA.x) * qs);
      o.u[1] = pkbf((x[2] * tA.z - x[3] * tA.w) * qs, (x[2] * tA.w + x[3] * tA.z) * qs);
      o.u[2] = pkbf((x[4] * tB.x - x[5] * tB.y) * qs, (x[4] * tB.y + x[5] * tB.x) * qs);
      o.u[3] = pkbf((x[6] * tB.z - x[7] * tB.w) * qs, (x[6] * tB.w + x[7] * tB.z) * qs);
      *reinterpret_cast<uint4*>(O + (size_t)grow * D_MODEL + cbase + lc * 8) = o.v;
    }
  } else {
    const int vc0 = (col0 - 2048) + wcol;
    const int h = vc0 >> 6;
    const int b = row0 >> 11;
    const int s0 = (row0 & (S_LEN - 1)) + wrow;
#pragma unroll
    for (int rg = 0; rg < 8; ++rg) {
      const int dk = rg * 8 + lr;
      const bf16x8 vv = ld8(&T[dk][lc * 8]);
      *reinterpret_cast<bf16x8*>(
          VTo + ((size_t)((b << 4) + h) * 64 + dk) * S_LEN + s0 + lc * 8) = vv;
    }
  }
}

// ---------------------------------------------------------------- attention
// Flash, causal, no running max (Q pre-scaled by 0.125*log2e; scores O(5)).
// S^T (A=K, B=Q): C-layout lane holds q=l15, keys=l4*4+r = the B-fragment of
// mfma_f32_16x16x16bf16_1k -> P feeds PV fully in-register. Register-pressure
// budget (round-7 lesson: spill at ~150 live): kf/s transient per-t, direct
// LDS staging (no reg prefetch), pf[2][4] kept so V-frags load once per d.
__global__ __launch_bounds__(256) void attn5_k(
    const unsigned short* __restrict__ Q, const unsigned short* __restrict__ K,
    const unsigned short* __restrict__ VT, unsigned short* __restrict__ O) {
  const int pair = blockIdx.x;  // 0..7
  const int h = blockIdx.y;
  const int b = blockIdx.z;
  const int tid = threadIdx.x;
  const int w = tid >> 6;
  const int lane = tid & 63;
  const int l15 = lane & 15;
  const int l4 = lane >> 4;

  __shared__ __align__(16) unsigned short Ks[64][72];
  __shared__ __align__(16) unsigned short Vs[64][72];  // Vs[dk][key]
#if !HAVE_MFMA16
  __shared__ __align__(16) unsigned short Ps[4][32][72];
#endif

  const f32x4 fz = {0.f, 0.f, 0.f, 0.f};
  const unsigned short* kbase = K + (size_t)b * S_LEN * D_MODEL + h * D_HEAD;
  const unsigned short* vbase = VT + (size_t)((b << 4) + h) * 64 * S_LEN;

  const int rr = tid >> 3;        // staging row 0..31 (+32 on 2nd chunk)
  const int c8 = (tid & 7) * 8;   // staging 8-short chunk

  for (int half = 0; half < 2; ++half) {
    const int qt = half ? (15 - pair) : pair;
    const int qb = qt * 128;
    const int qw0 = qb + w * 32;

    bf16x8 qf[2][2];
#pragma unroll
    for (int t = 0; t < 2; ++t)
#pragma unroll
      for (int kc = 0; kc < 2; ++kc)
        qf[t][kc] = ld8(Q + (size_t)(b * S_LEN + qw0 + t * 16 + l15) * D_MODEL +
                        h * D_HEAD + kc * 32 + l4 * 8);

    f32x4 o[4][2];
#pragma unroll
    for (int d = 0; d < 4; ++d)
#pragma unroll
      for (int t = 0; t < 2; ++t) o[d][t] = fz;
    float lsum[2] = {0.f, 0.f};

    const int nkt = qb / 64 + 2;
    for (int kt = 0; kt < nkt; ++kt) {
      const int kb0 = kt * 64;
#pragma unroll
      for (int it = 0; it < 2; ++it) {
        *reinterpret_cast<uint4*>(&Ks[rr + it * 32][c8]) =
            *reinterpret_cast<const uint4*>(kbase + (size_t)(kb0 + rr + it * 32) * D_MODEL + c8);
        *reinterpret_cast<uint4*>(&Vs[rr + it * 32][c8]) =
            *reinterpret_cast<const uint4*>(vbase + (size_t)(rr + it * 32) * S_LEN + kb0 + c8);
      }
      __syncthreads();

      if (kb0 <= qw0 + 31) {
        bf16x4 pf[2][4];
#pragma unroll
        for (int t = 0; t < 2; ++t) {
          // ---- S^T = K Q^T (transient kf, s: 8+16 regs)
          f32x4 s[4];
#pragma unroll
          for (int n = 0; n < 4; ++n) {
            const bf16x8 kf0 = ld8(&Ks[n * 16 + l15][l4 * 8]);
            const bf16x8 kf1 = ld8(&Ks[n * 16 + l15][32 + l4 * 8]);
            f32x4 a0 = __builtin_amdgcn_mfma_f32_16x16x32_bf16(kf0, qf[t][0], fz, 0, 0, 0);
            s[n] = __builtin_amdgcn_mfma_f32_16x16x32_bf16(kf1, qf[t][1], a0, 0, 0, 0);
          }
          // ---- exp2 + causal mask + per-lane row-sum + pack to bf16
          const bool full = (kb0 + 63 <= qw0 + t * 16);
          const int q = qw0 + t * 16 + l15;
          float su = lsum[t];
#pragma unroll
          for (int n = 0; n < 4; ++n) {
            float e[4];
            if (full) {
#pragma unroll
              for (int r = 0; r < 4; ++r) e[r] = exp2f(s[n][r]);
            } else {
#pragma unroll
              for (int r = 0; r < 4; ++r) {
                const int key = kb0 + n * 16 + l4 * 4 + r;
                const float v = exp2f(s[n][r]);
                e[r] = (key <= q) ? v : 0.f;
              }
            }
            su += (e[0] + e[1]) + (e[2] + e[3]);
            union { unsigned int u[2]; bf16x4 v; } pk;
            pk.u[0] = pkbf(e[0], e[1]);
            pk.u[1] = pkbf(e[2], e[3]);
            pf[t][n] = pk.v;
          }
          lsum[t] = su;
        }

        // ---- O^T += V^T P^T (V-frags loaded once per d, shared by both t)
#if HAVE_MFMA16
#pragma unroll
        for (int d = 0; d < 4; ++d) {
          bf16x4 vfc[4];
#pragma unroll
          for (int c = 0; c < 4; ++c) vfc[c] = ld4(&Vs[d * 16 + l15][c * 16 + l4 * 4]);
#pragma unroll
          for (int t = 0; t < 2; ++t)
#pragma unroll
            for (int c = 0; c < 4; ++c)
              o[d][t] = __builtin_amdgcn_mfma_f32_16x16x16bf16_1k(vfc[c], pf[t][c], o[d][t], 0, 0, 0);
        }
#else
#pragma unroll
        for (int t = 0; t < 2; ++t)
#pragma unroll
          for (int n = 0; n < 4; ++n)
            *reinterpret_cast<bf16x4*>(&Ps[w][t * 16 + l15][n * 16 + l4 * 4]) = pf[t][n];
        bf16x8 pfr[2][2], vf8[4][2];
#pragma unroll
        for (int t = 0; t < 2; ++t)
#pragma unroll
          for (int kc = 0; kc < 2; ++kc)
            pfr[t][kc] = ld8(&Ps[w][t * 16 + l15][kc * 32 + l4 * 8]);
#pragma unroll
        for (int d = 0; d < 4; ++d)
#pragma unroll
          for (int kc = 0; kc < 2; ++kc)
            vf8[d][kc] = ld8(&Vs[d * 16 + l15][kc * 32 + l4 * 8]);
#pragma unroll
        for (int d = 0; d < 4; ++d)
#pragma unroll
          for (int t = 0; t < 2; ++t) {
            o[d][t] = __builtin_amdgcn_mfma_f32_16x16x32_bf16(vf8[d][0], pfr[t][0], o[d][t], 0, 0, 0);
            o[d][t] = __builtin_amdgcn_mfma_f32_16x16x32_bf16(vf8[d][1], pfr[t][1], o[d][t], 0, 0, 0);
          }
#endif
      }
      __syncthreads();
    }

    // lsum lives per-lane at q=l15; reduce across quads (lane bits 4,5)
#pragma unroll
    for (int t = 0; t < 2; ++t) {
      float s = lsum[t];
      s += __shfl_xor(s, 16);
      s += __shfl_xor(s, 32);
      const float li = 1.0f / s;
      unsigned short* op = O + (size_t)(b * S_LEN + qw0 + t * 16 + l15) * D_MODEL +
                           h * D_HEAD + l4 * 4;
#pragma unroll
      for (int d = 0; d < 4; ++d) {
        union { unsigned int u[2]; uint2 v; } ov;
        ov.u[0] = pkbf(o[d][t][0] * li, o[d][t][1] * li);
        ov.u[1] = pkbf(o[d][t][2] * li, o[d][t][3] * li);
        *reinterpret_cast<uint2*>(op + d * 16) = ov.v;
      }
    }
  }
}

// ---------------------------------------------------------------- launch
extern "C" void kernel_launch(void* const* d_in, const int* in_sizes, int n_in,
                              void* d_out, int out_size, void* d_ws, size_t ws_size,
                              hipStream_t stream) {
  const float* x  = (const float*)d_in[0];
  const float* Wq = (const float*)d_in[1];
  const float* Wk = (const float*)d_in[2];
  const float* Wv = (const float*)d_in[3];
  const float* Wo = (const float*)d_in[4];
  const int* pos  = (const int*)d_in[5];
  float* out = (float*)d_out;

  char* ws = (char*)d_ws;
  const size_t big = (size_t)M_ROWS * D_MODEL * 2;  // 16 MiB
  const size_t wsz = (size_t)D_MODEL * D_MODEL * 2; // 2 MiB
  unsigned short* xb  = (unsigned short*)(ws + 0 * big);
  unsigned short* Qb  = (unsigned short*)(ws + 1 * big);  // attn out aliases Qb
  unsigned short* Kb  = (unsigned short*)(ws + 2 * big);
  unsigned short* VT  = (unsigned short*)(ws + 3 * big);
  unsigned short* Wqkvt = (unsigned short*)(ws + 4 * big);
  unsigned short* Wot   = (unsigned short*)(ws + 4 * big + 3 * wsz);
  float2* tab = (float2*)d_out;  // free scratch until final projection

  rope_tab_k<<<dim3(S_LEN * 32 / 256), 256, 0, stream>>>(pos, tab);
  cast_k<<<dim3(M_ROWS * D_MODEL / 2048), 256, 0, stream>>>(x, xb);
  wtrans_k<<<dim3(16, 16, 4), 256, 0, stream>>>(
      Wq, Wk, Wv, Wo, Wqkvt, Wqkvt + (size_t)D_MODEL * D_MODEL,
      Wqkvt + 2 * (size_t)D_MODEL * D_MODEL, Wot);
  gemm2_k<<<dim3(M_ROWS / 128, 3 * D_MODEL / 128), 256, 0, stream>>>(
      xb, Wqkvt, Qb, Kb, VT, nullptr, tab, 0);
  attn5_k<<<dim3(8, N_HEAD, B_N), 256, 0, stream>>>(Qb, Kb, VT, Qb);
  gemm2_k<<<dim3(M_ROWS / 128, D_MODEL / 128), 256, 0, stream>>>(
      Qb, Wot, nullptr, nullptr, nullptr, out, nullptr, 1);
}

// Round 9
// 277.939 us; speedup vs baseline: 1.1732x; 1.0845x over previous
//
#include <hip/hip_runtime.h>
#include <hip/hip_bf16.h>

#define B_N 4
#define S_LEN 2048
#define D_MODEL 1024
#define N_HEAD 16
#define D_HEAD 64
#define M_ROWS (B_N * S_LEN) /* 8192 */

typedef short bf16x8 __attribute__((ext_vector_type(8)));
typedef short bf16x4 __attribute__((ext_vector_type(4)));
typedef float f32x4 __attribute__((ext_vector_type(4)));

#if __has_builtin(__builtin_amdgcn_mfma_f32_16x16x16bf16_1k)
#define HAVE_MFMA16 1
#else
#define HAVE_MFMA16 0
#endif

__device__ __forceinline__ unsigned short f2bf(float f) {
  union { float f; unsigned int u; } v; v.f = f;
  unsigned int r = v.u + 0x7FFFu + ((v.u >> 16) & 1u);
  return (unsigned short)(r >> 16);
}
__device__ __forceinline__ float bf2f(unsigned short u) {
  union { unsigned int u; float f; } v; v.u = ((unsigned int)u) << 16;
  return v.f;
}
// packed f32x2 -> bf16x2 (v_cvt_pk_bf16_f32, RNE)
__device__ __forceinline__ unsigned int pkbf(float a, float b) {
  union { __hip_bfloat162 h; unsigned int u; } cv;
  cv.h = __float22bfloat162_rn(make_float2(a, b));
  return cv.u;
}
__device__ __forceinline__ bf16x8 ld8(const unsigned short* p) {
  return *reinterpret_cast<const bf16x8*>(p);
}
__device__ __forceinline__ bf16x4 ld4(const unsigned short* p) {
  return *reinterpret_cast<const bf16x4*>(p);
}
__device__ __forceinline__ void glds16(const unsigned short* g, unsigned short* l) {
  __builtin_amdgcn_global_load_lds(
      (const __attribute__((address_space(1))) unsigned int*)g,
      (__attribute__((address_space(3))) unsigned int*)l, 16, 0, 0);
}

// ---------------------------------------------------------------- rope table
__global__ __launch_bounds__(256) void rope_tab_k(const int* __restrict__ pos,
                                                  float2* __restrict__ tab) {
  const int idx = blockIdx.x * 256 + threadIdx.x;
  const int s = idx >> 5;
  const int i = idx & 31;
  const float inv = exp2f(-(float)i * 0.41524101186092029f);  // log2(1e4)/32
  const float ang = (float)pos[s] * inv;
  tab[idx] = make_float2(cosf(ang), sinf(ang));
}

// ---------------------------------------------------------------- cast x
__global__ __launch_bounds__(256) void cast_k(const float* __restrict__ X,
                                              unsigned short* __restrict__ Y) {
  const size_t i = ((size_t)blockIdx.x * 256 + threadIdx.x) * 8;
  const float4 a = *reinterpret_cast<const float4*>(X + i);
  const float4 b = *reinterpret_cast<const float4*>(X + i + 4);
  union { unsigned int u[4]; uint4 v; } o;
  o.u[0] = pkbf(a.x, a.y); o.u[1] = pkbf(a.z, a.w);
  o.u[2] = pkbf(b.x, b.y); o.u[3] = pkbf(b.z, b.w);
  *reinterpret_cast<uint4*>(Y + i) = o.v;
}

// ---------------------------------------------------------------- transpose
__global__ __launch_bounds__(256) void wtrans_k(
    const float* __restrict__ W0, const float* __restrict__ W1,
    const float* __restrict__ W2, const float* __restrict__ W3,
    unsigned short* __restrict__ T0, unsigned short* __restrict__ T1,
    unsigned short* __restrict__ T2, unsigned short* __restrict__ T3) {
  const int z = blockIdx.z;
  const float* __restrict__ W = (z == 0) ? W0 : (z == 1) ? W1 : (z == 2) ? W2 : W3;
  unsigned short* __restrict__ T = (z == 0) ? T0 : (z == 1) ? T1 : (z == 2) ? T2 : T3;
  __shared__ __align__(16) unsigned short tile[64][72];
  const int kb = blockIdx.x * 64;
  const int nb = blockIdx.y * 64;
#pragma unroll
  for (int it = 0; it < 2; ++it) {
    const int chunk = it * 256 + threadIdx.x;
    const int r = chunk >> 3;
    const int c8 = (chunk & 7) * 8;
    const float* src = W + (size_t)(kb + r) * D_MODEL + nb + c8;
    const float4 a = *reinterpret_cast<const float4*>(src);
    const float4 b = *reinterpret_cast<const float4*>(src + 4);
    union { unsigned int u[4]; uint4 v; } o;
    o.u[0] = pkbf(a.x, a.y); o.u[1] = pkbf(a.z, a.w);
    o.u[2] = pkbf(b.x, b.y); o.u[3] = pkbf(b.z, b.w);
    *reinterpret_cast<uint4*>(&tile[r][c8]) = o.v;
  }
  __syncthreads();
#pragma unroll
  for (int it = 0; it < 2; ++it) {
    const int chunk = it * 256 + threadIdx.x;
    const int n = chunk >> 3;
    const int k8 = (chunk & 7) * 8;
    __align__(16) unsigned short vals[8];
#pragma unroll
    for (int j = 0; j < 8; ++j) vals[j] = tile[k8 + j][n];
    *reinterpret_cast<uint4*>(T + (size_t)(nb + n) * D_MODEL + kb + k8) =
        *reinterpret_cast<const uint4*>(vals);
  }
}

// ---------------------------------------------------------------- GEMM
// 128x128 tile, BK=32, global_load_lds staging, 4 waves x (4x4 frags).
// mode 0 (QKV, N=3072): [0,1024)->Qo (rope, pre-scaled by 0.125*log2e),
//   [1024,2048)->Ko (rope), [2048,3072)->VTo transposed. Full-line stores
//   via wave-private LDS tile. mode 1: fp32 out.
__global__ __launch_bounds__(256) void gemm2_k(
    const unsigned short* __restrict__ A, const unsigned short* __restrict__ W,
    unsigned short* __restrict__ Qo, unsigned short* __restrict__ Ko,
    unsigned short* __restrict__ VTo, float* __restrict__ OF,
    const float2* __restrict__ tab, const int mode) {
  __shared__ __align__(16) unsigned short smem[4][64][68];
  unsigned short* As = &smem[0][0][0];
  unsigned short* Bs = As + 128 * 32;

  const int tid = threadIdx.x;
  const int lane = tid & 63;
  const int w = tid >> 6;
  const int l15 = lane & 15;
  const int l4 = lane >> 4;

  const int row0 = blockIdx.x * 128;
  const int col0 = blockIdx.y * 128;

  const int srow = w * 32 + (lane >> 2);
  const int scol = (lane & 3) * 8;
  const unsigned short* ga = A + (size_t)(row0 + srow) * D_MODEL + scol;
  const unsigned short* gb = W + (size_t)(col0 + srow) * D_MODEL + scol;
  unsigned short* la = &As[(w * 32) * 32];
  unsigned short* lb = &Bs[(w * 32) * 32];

  const int wrow = (w & 1) * 64;
  const int wcol = (w >> 1) * 64;

  f32x4 acc[4][4];
  const f32x4 fz = {0.f, 0.f, 0.f, 0.f};
#pragma unroll
  for (int m = 0; m < 4; ++m)
#pragma unroll
    for (int n = 0; n < 4; ++n) acc[m][n] = fz;

  for (int kb = 0; kb < D_MODEL; kb += 32) {
    glds16(ga + kb, la);
    glds16(ga + 16 * D_MODEL + kb, la + 16 * 32);
    glds16(gb + kb, lb);
    glds16(gb + 16 * D_MODEL + kb, lb + 16 * 32);
    __syncthreads();
    bf16x8 af[4], bfr[4];
#pragma unroll
    for (int m = 0; m < 4; ++m) af[m] = ld8(&As[(wrow + m * 16 + l15) * 32 + l4 * 8]);
#pragma unroll
    for (int n = 0; n < 4; ++n) bfr[n] = ld8(&Bs[(wcol + n * 16 + l15) * 32 + l4 * 8]);
#pragma unroll
    for (int m = 0; m < 4; ++m)
#pragma unroll
      for (int n = 0; n < 4; ++n)
        acc[m][n] = __builtin_amdgcn_mfma_f32_16x16x32_bf16(af[m], bfr[n], acc[m][n], 0, 0, 0);
    __syncthreads();
  }

  if (mode == 1) {
#pragma unroll
    for (int n = 0; n < 4; ++n) {
      const int gcol = col0 + wcol + n * 16 + l15;
#pragma unroll
      for (int m = 0; m < 4; ++m)
#pragma unroll
        for (int r = 0; r < 4; ++r)
          OF[(size_t)(row0 + wrow + m * 16 + l4 * 4 + r) * D_MODEL + gcol] = acc[m][n][r];
    }
    return;
  }

  unsigned short (*T)[68] = (unsigned short(*)[68]) & smem[w];  // wave-private
  const bool isV = (col0 >= 2048);
  if (!isV) {
#pragma unroll
    for (int m = 0; m < 4; ++m)
#pragma unroll
      for (int n = 0; n < 4; ++n)
#pragma unroll
        for (int r = 0; r < 4; ++r)
          T[m * 16 + l4 * 4 + r][n * 16 + l15] = f2bf(acc[m][n][r]);
  } else {
#pragma unroll
    for (int m = 0; m < 4; ++m)
#pragma unroll
      for (int n = 0; n < 4; ++n)
#pragma unroll
        for (int r = 0; r < 4; ++r)
          T[n * 16 + l15][m * 16 + l4 * 4 + r] = f2bf(acc[m][n][r]);
  }

  const int lr = lane >> 3;
  const int lc = lane & 7;
  if (!isV) {
    const bool isQ = (col0 < 1024);
    unsigned short* O = isQ ? Qo : Ko;
    // fold softmax scale into Q: 1/sqrt(64) * log2(e)
    const float qs = isQ ? 0.18033688011112042f : 1.0f;
    const int cbase = (col0 & 1023) + wcol;
#pragma unroll
    for (int rg = 0; rg < 8; ++rg) {
      const int trow = rg * 8 + lr;
      const int grow = row0 + wrow + trow;
      const int s = grow & (S_LEN - 1);
      const bf16x8 vv = ld8(&T[trow][lc * 8]);
      const float4 tA = *reinterpret_cast<const float4*>(&tab[s * 32 + lc * 4]);
      const float4 tB = *reinterpret_cast<const float4*>(&tab[s * 32 + lc * 4 + 2]);
      float x[8];
#pragma unroll
      for (int j = 0; j < 8; ++j) x[j] = bf2f((unsigned short)vv[j]);
      union { unsigned int u[4]; uint4 v; } o;
      o.u[0] = pkbf((x[0] * tA.x - x[1] * tA.y) * qs, (x[0] * tA.y + x[1] * tA.x) * qs);
      o.u[1] = pkbf((x[2] * tA.z - x[3] * tA.w) * qs, (x[2] * tA.w + x[3] * tA.z) * qs);
      o.u[2] = pkbf((x[4] * tB.x - x[5] * tB.y) * qs, (x[4] * tB.y + x[5] * tB.x) * qs);
      o.u[3] = pkbf((x[6] * tB.z - x[7] * tB.w) * qs, (x[6] * tB.w + x[7] * tB.z) * qs);
      *reinterpret_cast<uint4*>(O + (size_t)grow * D_MODEL + cbase + lc * 8) = o.v;
    }
  } else {
    const int vc0 = (col0 - 2048) + wcol;
    const int h = vc0 >> 6;
    const int b = row0 >> 11;
    const int s0 = (row0 & (S_LEN - 1)) + wrow;
#pragma unroll
    for (int rg = 0; rg < 8; ++rg) {
      const int dk = rg * 8 + lr;
      const bf16x8 vv = ld8(&T[dk][lc * 8]);
      *reinterpret_cast<bf16x8*>(
          VTo + ((size_t)((b << 4) + h) * 64 + dk) * S_LEN + s0 + lc * 8) = vv;
    }
  }
}

// ---------------------------------------------------------------- attention
// Flash, causal, no running max (Q pre-scaled by 0.125*log2e; scores O(5)).
// S^T (A=K, B=Q): C-layout lane holds q=l15, keys=l4*4+r = the B-fragment of
// mfma_f32_16x16x16bf16_1k -> P feeds PV fully in-register.
// 512 threads = 8 waves x 16 q = 128 q/block (same work/staging as r8's 4x32,
// but 4 waves/SIMD for cross-wave MFMA/VALU overlap). K/V staging
// double-buffered through regs (fits: ~70 live VGPRs with 16 q/wave).
__global__ __launch_bounds__(512) void attn6_k(
    const unsigned short* __restrict__ Q, const unsigned short* __restrict__ K,
    const unsigned short* __restrict__ VT, unsigned short* __restrict__ O) {
  const int pair = blockIdx.x;  // 0..7
  const int h = blockIdx.y;
  const int b = blockIdx.z;
  const int tid = threadIdx.x;
  const int w = tid >> 6;       // 0..7
  const int lane = tid & 63;
  const int l15 = lane & 15;
  const int l4 = lane >> 4;

  __shared__ __align__(16) unsigned short Ks[64][72];
  __shared__ __align__(16) unsigned short Vs[64][72];  // Vs[dk][key]
#if !HAVE_MFMA16
  __shared__ __align__(16) unsigned short Ps[8][16][72];
#endif

  const f32x4 fz = {0.f, 0.f, 0.f, 0.f};
  const unsigned short* kbase = K + (size_t)b * S_LEN * D_MODEL + h * D_HEAD;
  const unsigned short* vbase = VT + (size_t)((b << 4) + h) * 64 * S_LEN;

  const int rr = tid >> 3;        // staging row 0..63 (512 thr cover 64x64)
  const int c8 = (tid & 7) * 8;   // staging 8-short chunk

  for (int half = 0; half < 2; ++half) {
    const int qt = half ? (15 - pair) : pair;
    const int qb = qt * 128;
    const int qw0 = qb + w * 16;

    bf16x8 qf[2];
#pragma unroll
    for (int kc = 0; kc < 2; ++kc)
      qf[kc] = ld8(Q + (size_t)(b * S_LEN + qw0 + l15) * D_MODEL +
                   h * D_HEAD + kc * 32 + l4 * 8);

    f32x4 o[4];
#pragma unroll
    for (int d = 0; d < 4; ++d) o[d] = fz;
    float lsum = 0.f;

    const int nkt = qb / 64 + 2;
    // prefetch tile 0
    uint4 kreg = *reinterpret_cast<const uint4*>(kbase + (size_t)rr * D_MODEL + c8);
    uint4 vreg = *reinterpret_cast<const uint4*>(vbase + (size_t)rr * S_LEN + c8);

    for (int kt = 0; kt < nkt; ++kt) {
      const int kb0 = kt * 64;
      *reinterpret_cast<uint4*>(&Ks[rr][c8]) = kreg;
      *reinterpret_cast<uint4*>(&Vs[rr][c8]) = vreg;
      if (kt + 1 < nkt) {  // prefetch next tile; hides behind this tile's math
        const int nb0 = kb0 + 64;
        kreg = *reinterpret_cast<const uint4*>(kbase + (size_t)(nb0 + rr) * D_MODEL + c8);
        vreg = *reinterpret_cast<const uint4*>(vbase + (size_t)rr * S_LEN + nb0 + c8);
      }
      __syncthreads();

      if (kb0 <= qw0 + 15) {
        // ---- S^T = K Q^T : lane holds q=l15, key=kb0+n*16+l4*4+r
        f32x4 s[4];
#pragma unroll
        for (int n = 0; n < 4; ++n) {
          const bf16x8 kf0 = ld8(&Ks[n * 16 + l15][l4 * 8]);
          const bf16x8 kf1 = ld8(&Ks[n * 16 + l15][32 + l4 * 8]);
          f32x4 a0 = __builtin_amdgcn_mfma_f32_16x16x32_bf16(kf0, qf[0], fz, 0, 0, 0);
          s[n] = __builtin_amdgcn_mfma_f32_16x16x32_bf16(kf1, qf[1], a0, 0, 0, 0);
        }
        // ---- exp2 + causal mask + per-lane row-sum + pack to bf16
        bf16x4 pf[4];
        const bool full = (kb0 + 63 <= qw0);
        const int q = qw0 + l15;
        float su = lsum;
#pragma unroll
        for (int n = 0; n < 4; ++n) {
          float e[4];
          if (full) {
#pragma unroll
            for (int r = 0; r < 4; ++r) e[r] = exp2f(s[n][r]);
          } else {
#pragma unroll
            for (int r = 0; r < 4; ++r) {
              const int key = kb0 + n * 16 + l4 * 4 + r;
              const float v = exp2f(s[n][r]);
              e[r] = (key <= q) ? v : 0.f;
            }
          }
          su += (e[0] + e[1]) + (e[2] + e[3]);
          union { unsigned int u[2]; bf16x4 v; } pk;
          pk.u[0] = pkbf(e[0], e[1]);
          pk.u[1] = pkbf(e[2], e[3]);
          pf[n] = pk.v;
        }
        lsum = su;

        // ---- O^T += V^T P^T (P in-register as B-operand)
#if HAVE_MFMA16
#pragma unroll
        for (int d = 0; d < 4; ++d) {
          bf16x4 vfc[4];
#pragma unroll
          for (int c = 0; c < 4; ++c) vfc[c] = ld4(&Vs[d * 16 + l15][c * 16 + l4 * 4]);
#pragma unroll
          for (int c = 0; c < 4; ++c)
            o[d] = __builtin_amdgcn_mfma_f32_16x16x16bf16_1k(vfc[c], pf[c], o[d], 0, 0, 0);
        }
#else
#pragma unroll
        for (int n = 0; n < 4; ++n)
          *reinterpret_cast<bf16x4*>(&Ps[w][l15][n * 16 + l4 * 4]) = pf[n];
        bf16x8 pfr[2];
#pragma unroll
        for (int kc = 0; kc < 2; ++kc)
          pfr[kc] = ld8(&Ps[w][l15][kc * 32 + l4 * 8]);
#pragma unroll
        for (int d = 0; d < 4; ++d) {
          const bf16x8 vf0 = ld8(&Vs[d * 16 + l15][l4 * 8]);
          const bf16x8 vf1 = ld8(&Vs[d * 16 + l15][32 + l4 * 8]);
          o[d] = __builtin_amdgcn_mfma_f32_16x16x32_bf16(vf0, pfr[0], o[d], 0, 0, 0);
          o[d] = __builtin_amdgcn_mfma_f32_16x16x32_bf16(vf1, pfr[1], o[d], 0, 0, 0);
        }
#endif
      }
      __syncthreads();
    }

    // lsum lives per-lane at q=l15; reduce across quads (lane bits 4,5)
    float s = lsum;
    s += __shfl_xor(s, 16);
    s += __shfl_xor(s, 32);
    const float li = 1.0f / s;
    unsigned short* op = O + (size_t)(b * S_LEN + qw0 + l15) * D_MODEL +
                         h * D_HEAD + l4 * 4;
#pragma unroll
    for (int d = 0; d < 4; ++d) {
      union { unsigned int u[2]; uint2 v; } ov;
      ov.u[0] = pkbf(o[d][0] * li, o[d][1] * li);
      ov.u[1] = pkbf(o[d][2] * li, o[d][3] * li);
      *reinterpret_cast<uint2*>(op + d * 16) = ov.v;
    }
  }
}

// ---------------------------------------------------------------- launch
extern "C" void kernel_launch(void* const* d_in, const int* in_sizes, int n_in,
                              void* d_out, int out_size, void* d_ws, size_t ws_size,
                              hipStream_t stream) {
  const float* x  = (const float*)d_in[0];
  const float* Wq = (const float*)d_in[1];
  const float* Wk = (const float*)d_in[2];
  const float* Wv = (const float*)d_in[3];
  const float* Wo = (const float*)d_in[4];
  const int* pos  = (const int*)d_in[5];
  float* out = (float*)d_out;

  char* ws = (char*)d_ws;
  const size_t big = (size_t)M_ROWS * D_MODEL * 2;  // 16 MiB
  const size_t wsz = (size_t)D_MODEL * D_MODEL * 2; // 2 MiB
  unsigned short* xb  = (unsigned short*)(ws + 0 * big);
  unsigned short* Qb  = (unsigned short*)(ws + 1 * big);  // attn out aliases Qb
  unsigned short* Kb  = (unsigned short*)(ws + 2 * big);
  unsigned short* VT  = (unsigned short*)(ws + 3 * big);
  unsigned short* Wqkvt = (unsigned short*)(ws + 4 * big);
  unsigned short* Wot   = (unsigned short*)(ws + 4 * big + 3 * wsz);
  float2* tab = (float2*)d_out;  // free scratch until final projection

  rope_tab_k<<<dim3(S_LEN * 32 / 256), 256, 0, stream>>>(pos, tab);
  cast_k<<<dim3(M_ROWS * D_MODEL / 2048), 256, 0, stream>>>(x, xb);
  wtrans_k<<<dim3(16, 16, 4), 256, 0, stream>>>(
      Wq, Wk, Wv, Wo, Wqkvt, Wqkvt + (size_t)D_MODEL * D_MODEL,
      Wqkvt + 2 * (size_t)D_MODEL * D_MODEL, Wot);
  gemm2_k<<<dim3(M_ROWS / 128, 3 * D_MODEL / 128), 256, 0, stream>>>(
      xb, Wqkvt, Qb, Kb, VT, nullptr, tab, 0);
  attn6_k<<<dim3(8, N_HEAD, B_N), 512, 0, stream>>>(Qb, Kb, VT, Qb);
  gemm2_k<<<dim3(M_ROWS / 128, D_MODEL / 128), 256, 0, stream>>>(
      Qb, Wot, nullptr, nullptr, nullptr, out, nullptr, 1);
}